// Round 4
// baseline (1476.035 us; speedup 1.0000x reference)
//
#include <hip/hip_runtime.h>
#include <math.h>

#define LR 0.1f
#define EPS 1e-6f

constexpr int B_ = 16, S_ = 4096, DK_ = 256, DV_ = 256;

// ---------------------------------------------------------------------------
// DPP butterfly add over 16-lane groups (pure VALU, verified correct in R3).
// ---------------------------------------------------------------------------
#define DPP_ADD(x, ctrl) \
    ((x) + __int_as_float(__builtin_amdgcn_update_dpp(0, __float_as_int(x), (ctrl), 0xF, 0xF, true)))

__device__ __forceinline__ float red16(float x) {
    x = DPP_ADD(x, 0xB1);   // quad_perm [1,0,3,2]  : xor1
    x = DPP_ADD(x, 0x4E);   // quad_perm [2,3,0,1]  : xor2
    x = DPP_ADD(x, 0x141);  // row_half_mirror      : xor7
    x = DPP_ADD(x, 0x140);  // row_mirror           : xor15
    return x;
}

// ---------------------------------------------------------------------------
// Kernel A: rnorm[b*S + t] = 1 / (||key[b,t,:]|| + EPS)
// ---------------------------------------------------------------------------
__global__ __launch_bounds__(256)
void knorm_kernel(const float* __restrict__ key, float* __restrict__ rnorm) {
    const int lane = threadIdx.x & 63;
    const int wid  = threadIdx.x >> 6;
    const int g    = lane >> 4;
    const int sub  = lane & 15;
    const int row  = blockIdx.x * 16 + wid * 4 + g;   // flattened b*S + t

    const float* kp = key + (size_t)row * DK_ + (sub << 2);
    float s = 0.0f;
#pragma unroll
    for (int j = 0; j < 4; ++j) {
        const float4 k4 = *reinterpret_cast<const float4*>(kp + 64 * j);
        s += k4.x * k4.x + k4.y * k4.y + k4.z * k4.z + k4.w * k4.w;
    }
    s = red16(s);
    if (sub == 0) rnorm[row] = 1.0f / (sqrtf(s) + EPS);
}

// ---------------------------------------------------------------------------
// Main kernel: 1024 waves; wave owns 4 rows (16-lane group per row).
// 8-stage rotating prefetch with static register names; sched_barrier(0)
// after each ISSUE pins the loads early (defeats compiler load-sinking,
// which flattened R3's pipeline — VGPR was 40, too small to hold stages).
// ISSUE also precomputes CR = 1.1*rn^2 and LV = 0.1*v*rn off the critical
// path, so post-reduction chain is just coeff = fma(CR, p, -LV).
// ---------------------------------------------------------------------------
#define ISSUE(K0, K1, K2, K3, CR, LV, idx_)                                   \
    do {                                                                      \
        const int ii = ((idx_) < S_) ? (idx_) : (S_ - 1);                     \
        const float* kp = kbase + (size_t)ii * DK_ + (sub << 2);              \
        K0 = *reinterpret_cast<const float4*>(kp);                            \
        K1 = *reinterpret_cast<const float4*>(kp + 64);                       \
        K2 = *reinterpret_cast<const float4*>(kp + 128);                      \
        K3 = *reinterpret_cast<const float4*>(kp + 192);                      \
        const float v_ = vrow[(size_t)ii * DV_];                              \
        if (PRECOMP) {                                                        \
            const float rn_ = rbase[ii];                                      \
            CR = (1.0f + LR) * rn_ * rn_;                                     \
            LV = LR * v_ * rn_;                                               \
        } else {                                                              \
            CR = 0.0f; /* unused */                                           \
            LV = v_;   /* carry raw v */                                      \
        }                                                                     \
        __builtin_amdgcn_sched_barrier(0);                                    \
    } while (0)

#define STEP(K0, K1, K2, K3, CR, LV)                                          \
    do {                                                                      \
        float p0 = K0.x * m0.x + K0.y * m0.y + K0.z * m0.z + K0.w * m0.w;     \
        float p1 = K1.x * m1.x + K1.y * m1.y + K1.z * m1.z + K1.w * m1.w;     \
        float p2 = K2.x * m2.x + K2.y * m2.y + K2.z * m2.z + K2.w * m2.w;     \
        float p3 = K3.x * m3.x + K3.y * m3.y + K3.z * m3.z + K3.w * m3.w;     \
        float p = (p0 + p1) + (p2 + p3);                                      \
        p = red16(p);                                                         \
        float coeff;                                                          \
        if (PRECOMP) {                                                        \
            coeff = fmaf(CR, p, -LV);                                         \
        } else {                                                              \
            float s0 = K0.x * K0.x + K0.y * K0.y + K0.z * K0.z + K0.w * K0.w; \
            float s1 = K1.x * K1.x + K1.y * K1.y + K1.z * K1.z + K1.w * K1.w; \
            float s2 = K2.x * K2.x + K2.y * K2.y + K2.z * K2.z + K2.w * K2.w; \
            float s3 = K3.x * K3.x + K3.y * K3.y + K3.z * K3.z + K3.w * K3.w; \
            float s = red16((s0 + s1) + (s2 + s3));                           \
            const float rn_ = 1.0f / (sqrtf(s) + EPS);                        \
            coeff = fmaf((1.0f + LR) * rn_ * rn_, p, -(LR * LV * rn_));       \
        }                                                                     \
        m0.x = fmaf(-coeff, K0.x, m0.x); m0.y = fmaf(-coeff, K0.y, m0.y);     \
        m0.z = fmaf(-coeff, K0.z, m0.z); m0.w = fmaf(-coeff, K0.w, m0.w);     \
        m1.x = fmaf(-coeff, K1.x, m1.x); m1.y = fmaf(-coeff, K1.y, m1.y);     \
        m1.z = fmaf(-coeff, K1.z, m1.z); m1.w = fmaf(-coeff, K1.w, m1.w);     \
        m2.x = fmaf(-coeff, K2.x, m2.x); m2.y = fmaf(-coeff, K2.y, m2.y);     \
        m2.z = fmaf(-coeff, K2.z, m2.z); m2.w = fmaf(-coeff, K2.w, m2.w);     \
        m3.x = fmaf(-coeff, K3.x, m3.x); m3.y = fmaf(-coeff, K3.y, m3.y);     \
        m3.z = fmaf(-coeff, K3.z, m3.z); m3.w = fmaf(-coeff, K3.w, m3.w);     \
    } while (0)

template <bool PRECOMP>
__global__ __launch_bounds__(256, 1)
void delta_kernel(const float* __restrict__ memory, const float* __restrict__ key,
                  const float* __restrict__ value, const float* __restrict__ rnorm,
                  float* __restrict__ out) {
    const int lane = threadIdx.x & 63;
    const int wid  = threadIdx.x >> 6;
    const int bid  = blockIdx.x;                       // 256 blocks
    const int b    = ((bid & 7) << 1) | (bid >> 7);    // XCD x -> batches 2x, 2x+1
    const int rblk = (((bid >> 3) & 15) << 2) | wid;   // 0..63
    const int g    = lane >> 4;
    const int sub  = lane & 15;
    const int row  = (rblk << 2) | g;                  // 0..255

    const float* kbase = key   + (size_t)b * S_ * DK_;
    const float* vrow  = value + ((size_t)b * S_) * DV_ + row;
    const float* rbase = rnorm + (size_t)b * S_;

    const size_t moff = ((size_t)b * DV_ + row) * DK_ + (sub << 2);
    float4 m0 = *reinterpret_cast<const float4*>(memory + moff);
    float4 m1 = *reinterpret_cast<const float4*>(memory + moff + 64);
    float4 m2 = *reinterpret_cast<const float4*>(memory + moff + 128);
    float4 m3 = *reinterpret_cast<const float4*>(memory + moff + 192);

    // 8-stage software pipeline (statically named registers)
    float4 kA0, kA1, kA2, kA3, kB0, kB1, kB2, kB3;
    float4 kC0, kC1, kC2, kC3, kD0, kD1, kD2, kD3;
    float4 kE0, kE1, kE2, kE3, kF0, kF1, kF2, kF3;
    float4 kG0, kG1, kG2, kG3, kH0, kH1, kH2, kH3;
    float cA, cB, cC, cD, cE, cF, cG, cH;
    float lA, lB, lC, lD, lE, lF, lG, lH;

    ISSUE(kA0, kA1, kA2, kA3, cA, lA, 0);
    ISSUE(kB0, kB1, kB2, kB3, cB, lB, 1);
    ISSUE(kC0, kC1, kC2, kC3, cC, lC, 2);
    ISSUE(kD0, kD1, kD2, kD3, cD, lD, 3);
    ISSUE(kE0, kE1, kE2, kE3, cE, lE, 4);
    ISSUE(kF0, kF1, kF2, kF3, cF, lF, 5);
    ISSUE(kG0, kG1, kG2, kG3, cG, lG, 6);
    ISSUE(kH0, kH1, kH2, kH3, cH, lH, 7);

    for (int t = 0; t < S_; t += 8) {
        STEP(kA0, kA1, kA2, kA3, cA, lA);
        ISSUE(kA0, kA1, kA2, kA3, cA, lA, t + 8);
        STEP(kB0, kB1, kB2, kB3, cB, lB);
        ISSUE(kB0, kB1, kB2, kB3, cB, lB, t + 9);
        STEP(kC0, kC1, kC2, kC3, cC, lC);
        ISSUE(kC0, kC1, kC2, kC3, cC, lC, t + 10);
        STEP(kD0, kD1, kD2, kD3, cD, lD);
        ISSUE(kD0, kD1, kD2, kD3, cD, lD, t + 11);
        STEP(kE0, kE1, kE2, kE3, cE, lE);
        ISSUE(kE0, kE1, kE2, kE3, cE, lE, t + 12);
        STEP(kF0, kF1, kF2, kF3, cF, lF);
        ISSUE(kF0, kF1, kF2, kF3, cF, lF, t + 13);
        STEP(kG0, kG1, kG2, kG3, cG, lG);
        ISSUE(kG0, kG1, kG2, kG3, cG, lG, t + 14);
        STEP(kH0, kH1, kH2, kH3, cH, lH);
        ISSUE(kH0, kH1, kH2, kH3, cH, lH, t + 15);
    }

    float* op = out + moff;
    *reinterpret_cast<float4*>(op)       = m0;
    *reinterpret_cast<float4*>(op + 64)  = m1;
    *reinterpret_cast<float4*>(op + 128) = m2;
    *reinterpret_cast<float4*>(op + 192) = m3;
}

// ---------------------------------------------------------------------------
extern "C" void kernel_launch(void* const* d_in, const int* in_sizes, int n_in,
                              void* d_out, int out_size, void* d_ws, size_t ws_size,
                              hipStream_t stream) {
    const float* memory = (const float*)d_in[0];   // (B, DV, DK) f32
    const float* key    = (const float*)d_in[1];   // (B, S, DK)  f32
    const float* value  = (const float*)d_in[2];   // (B, S, DV)  f32
    float*       out    = (float*)d_out;           // (B, DV, DK) f32
    float*       rnorm  = (float*)d_ws;

    const size_t rnorm_bytes = (size_t)B_ * S_ * sizeof(float);
    const bool precomp = (ws_size >= rnorm_bytes);

    if (precomp) {
        knorm_kernel<<<(B_ * S_) / 16, 256, 0, stream>>>(key, rnorm);
        delta_kernel<true><<<256, 256, 0, stream>>>(memory, key, value, rnorm, out);
    } else {
        delta_kernel<false><<<256, 256, 0, stream>>>(memory, key, value, nullptr, out);
    }
}

// Round 5
// 805.591 us; speedup vs baseline: 1.8322x; 1.8322x over previous
//
#include <hip/hip_runtime.h>
#include <math.h>

#define LR 0.1f
#define EPS 1e-6f

constexpr int B_ = 16, S_ = 4096, DK_ = 256, DV_ = 256;

// ---------------------------------------------------------------------------
// DPP butterfly add over 16-lane groups (pure VALU, verified in R3/R4).
// ---------------------------------------------------------------------------
#define DPP_ADD(x, ctrl) \
    ((x) + __int_as_float(__builtin_amdgcn_update_dpp(0, __float_as_int(x), (ctrl), 0xF, 0xF, true)))

__device__ __forceinline__ float red16(float x) {
    x = DPP_ADD(x, 0xB1);   // quad_perm [1,0,3,2]  : xor1
    x = DPP_ADD(x, 0x4E);   // quad_perm [2,3,0,1]  : xor2
    x = DPP_ADD(x, 0x141);  // row_half_mirror      : xor7
    x = DPP_ADD(x, 0x140);  // row_mirror           : xor15
    return x;
}

// ---------------------------------------------------------------------------
// Kernel A: rnorm[b*S + t] = 1 / (||key[b,t,:]|| + EPS)
// ---------------------------------------------------------------------------
__global__ __launch_bounds__(256)
void knorm_kernel(const float* __restrict__ key, float* __restrict__ rnorm) {
    const int lane = threadIdx.x & 63;
    const int wid  = threadIdx.x >> 6;
    const int g    = lane >> 4;
    const int sub  = lane & 15;
    const int row  = blockIdx.x * 16 + wid * 4 + g;   // flattened b*S + t

    const float* kp = key + (size_t)row * DK_ + (sub << 2);
    float s = 0.0f;
#pragma unroll
    for (int j = 0; j < 4; ++j) {
        const float4 k4 = *reinterpret_cast<const float4*>(kp + 64 * j);
        s += k4.x * k4.x + k4.y * k4.y + k4.z * k4.z + k4.w * k4.w;
    }
    s = red16(s);
    if (sub == 0) rnorm[row] = 1.0f / (sqrtf(s) + EPS);
}

// ---------------------------------------------------------------------------
// Main kernel: 1024 waves; wave owns 4 rows (16-lane group per row).
// 8-stage rotating prefetch. ISSUE is PURE LOADS (no arithmetic touches the
// loaded values -> no vmcnt drain inside ISSUE; R4's bug was computing
// CR/LV from rn/v right after issuing them, which stalled every ISSUE).
// All consumption happens in STEP, 7 stages later. sched_barrier(0) after
// each ISSUE keeps the loads pinned early.
// ---------------------------------------------------------------------------
#define ISSUE(K0, K1, K2, K3, V, R, idx_)                                     \
    do {                                                                      \
        const float* kp = kbase + (size_t)(idx_)*DK_ + (sub << 2);            \
        K0 = *reinterpret_cast<const float4*>(kp);                            \
        K1 = *reinterpret_cast<const float4*>(kp + 64);                       \
        K2 = *reinterpret_cast<const float4*>(kp + 128);                      \
        K3 = *reinterpret_cast<const float4*>(kp + 192);                      \
        V = vrow[(size_t)(idx_)*DV_];                                         \
        if (PRECOMP) R = rbase[(idx_)];                                       \
        __builtin_amdgcn_sched_barrier(0);                                    \
    } while (0)

#define STEP(K0, K1, K2, K3, V, R)                                            \
    do {                                                                      \
        float p0 = K0.x * m0.x + K0.y * m0.y + K0.z * m0.z + K0.w * m0.w;     \
        float p1 = K1.x * m1.x + K1.y * m1.y + K1.z * m1.z + K1.w * m1.w;     \
        float p2 = K2.x * m2.x + K2.y * m2.y + K2.z * m2.z + K2.w * m2.w;     \
        float p3 = K3.x * m3.x + K3.y * m3.y + K3.z * m3.z + K3.w * m3.w;     \
        float p = (p0 + p1) + (p2 + p3);                                      \
        p = red16(p);                                                         \
        float coeff;                                                          \
        if (PRECOMP) {                                                        \
            /* CR/LV independent of p -> scheduled in parallel with red16 */  \
            const float CR_ = (1.0f + LR) * R * R;                            \
            const float LV_ = LR * R * V;                                     \
            coeff = fmaf(CR_, p, -LV_);                                       \
        } else {                                                              \
            float s0 = K0.x * K0.x + K0.y * K0.y + K0.z * K0.z + K0.w * K0.w; \
            float s1 = K1.x * K1.x + K1.y * K1.y + K1.z * K1.z + K1.w * K1.w; \
            float s2 = K2.x * K2.x + K2.y * K2.y + K2.z * K2.z + K2.w * K2.w; \
            float s3 = K3.x * K3.x + K3.y * K3.y + K3.z * K3.z + K3.w * K3.w; \
            float s = red16((s0 + s1) + (s2 + s3));                           \
            const float rn_ = 1.0f / (sqrtf(s) + EPS);                        \
            coeff = fmaf((1.0f + LR) * rn_ * rn_, p, -(LR * rn_ * V));        \
        }                                                                     \
        m0.x = fmaf(-coeff, K0.x, m0.x); m0.y = fmaf(-coeff, K0.y, m0.y);     \
        m0.z = fmaf(-coeff, K0.z, m0.z); m0.w = fmaf(-coeff, K0.w, m0.w);     \
        m1.x = fmaf(-coeff, K1.x, m1.x); m1.y = fmaf(-coeff, K1.y, m1.y);     \
        m1.z = fmaf(-coeff, K1.z, m1.z); m1.w = fmaf(-coeff, K1.w, m1.w);     \
        m2.x = fmaf(-coeff, K2.x, m2.x); m2.y = fmaf(-coeff, K2.y, m2.y);     \
        m2.z = fmaf(-coeff, K2.z, m2.z); m2.w = fmaf(-coeff, K2.w, m2.w);     \
        m3.x = fmaf(-coeff, K3.x, m3.x); m3.y = fmaf(-coeff, K3.y, m3.y);     \
        m3.z = fmaf(-coeff, K3.z, m3.z); m3.w = fmaf(-coeff, K3.w, m3.w);     \
    } while (0)

template <bool PRECOMP>
__global__ __launch_bounds__(256, 1)
void delta_kernel(const float* __restrict__ memory, const float* __restrict__ key,
                  const float* __restrict__ value, const float* __restrict__ rnorm,
                  float* __restrict__ out) {
    const int lane = threadIdx.x & 63;
    const int wid  = threadIdx.x >> 6;
    const int bid  = blockIdx.x;                       // 256 blocks
    const int b    = ((bid & 7) << 1) | (bid >> 7);    // XCD x -> batches 2x, 2x+1
    const int rblk = (((bid >> 3) & 15) << 2) | wid;   // 0..63
    const int g    = lane >> 4;
    const int sub  = lane & 15;
    const int row  = (rblk << 2) | g;                  // 0..255

    const float* kbase = key   + (size_t)b * S_ * DK_;
    const float* vrow  = value + ((size_t)b * S_) * DV_ + row;
    const float* rbase = rnorm + (size_t)b * S_;

    const size_t moff = ((size_t)b * DV_ + row) * DK_ + (sub << 2);
    float4 m0 = *reinterpret_cast<const float4*>(memory + moff);
    float4 m1 = *reinterpret_cast<const float4*>(memory + moff + 64);
    float4 m2 = *reinterpret_cast<const float4*>(memory + moff + 128);
    float4 m3 = *reinterpret_cast<const float4*>(memory + moff + 192);

    // 8-stage software pipeline (statically named registers)
    float4 kA0, kA1, kA2, kA3, kB0, kB1, kB2, kB3;
    float4 kC0, kC1, kC2, kC3, kD0, kD1, kD2, kD3;
    float4 kE0, kE1, kE2, kE3, kF0, kF1, kF2, kF3;
    float4 kG0, kG1, kG2, kG3, kH0, kH1, kH2, kH3;
    float vA, vB, vC, vD, vE, vF, vG, vH;
    float rA = 0, rB = 0, rC = 0, rD = 0, rE = 0, rF = 0, rG = 0, rH = 0;

    ISSUE(kA0, kA1, kA2, kA3, vA, rA, 0);
    ISSUE(kB0, kB1, kB2, kB3, vB, rB, 1);
    ISSUE(kC0, kC1, kC2, kC3, vC, rC, 2);
    ISSUE(kD0, kD1, kD2, kD3, vD, rD, 3);
    ISSUE(kE0, kE1, kE2, kE3, vE, rE, 4);
    ISSUE(kF0, kF1, kF2, kF3, vF, rF, 5);
    ISSUE(kG0, kG1, kG2, kG3, vG, rG, 6);
    ISSUE(kH0, kH1, kH2, kH3, vH, rH, 7);

    // main loop: steps 0..4087, issuing 8..4095 (no clamp needed)
    for (int t = 0; t < S_ - 8; t += 8) {
        STEP(kA0, kA1, kA2, kA3, vA, rA);
        ISSUE(kA0, kA1, kA2, kA3, vA, rA, t + 8);
        STEP(kB0, kB1, kB2, kB3, vB, rB);
        ISSUE(kB0, kB1, kB2, kB3, vB, rB, t + 9);
        STEP(kC0, kC1, kC2, kC3, vC, rC);
        ISSUE(kC0, kC1, kC2, kC3, vC, rC, t + 10);
        STEP(kD0, kD1, kD2, kD3, vD, rD);
        ISSUE(kD0, kD1, kD2, kD3, vD, rD, t + 11);
        STEP(kE0, kE1, kE2, kE3, vE, rE);
        ISSUE(kE0, kE1, kE2, kE3, vE, rE, t + 12);
        STEP(kF0, kF1, kF2, kF3, vF, rF);
        ISSUE(kF0, kF1, kF2, kF3, vF, rF, t + 13);
        STEP(kG0, kG1, kG2, kG3, vG, rG);
        ISSUE(kG0, kG1, kG2, kG3, vG, rG, t + 14);
        STEP(kH0, kH1, kH2, kH3, vH, rH);
        ISSUE(kH0, kH1, kH2, kH3, vH, rH, t + 15);
    }

    // drain epilogue: last 8 steps, no more issues
    STEP(kA0, kA1, kA2, kA3, vA, rA);
    STEP(kB0, kB1, kB2, kB3, vB, rB);
    STEP(kC0, kC1, kC2, kC3, vC, rC);
    STEP(kD0, kD1, kD2, kD3, vD, rD);
    STEP(kE0, kE1, kE2, kE3, vE, rE);
    STEP(kF0, kF1, kF2, kF3, vF, rF);
    STEP(kG0, kG1, kG2, kG3, vG, rG);
    STEP(kH0, kH1, kH2, kH3, vH, rH);

    float* op = out + moff;
    *reinterpret_cast<float4*>(op)       = m0;
    *reinterpret_cast<float4*>(op + 64)  = m1;
    *reinterpret_cast<float4*>(op + 128) = m2;
    *reinterpret_cast<float4*>(op + 192) = m3;
}

// ---------------------------------------------------------------------------
extern "C" void kernel_launch(void* const* d_in, const int* in_sizes, int n_in,
                              void* d_out, int out_size, void* d_ws, size_t ws_size,
                              hipStream_t stream) {
    const float* memory = (const float*)d_in[0];   // (B, DV, DK) f32
    const float* key    = (const float*)d_in[1];   // (B, S, DK)  f32
    const float* value  = (const float*)d_in[2];   // (B, S, DV)  f32
    float*       out    = (float*)d_out;           // (B, DV, DK) f32
    float*       rnorm  = (float*)d_ws;

    const size_t rnorm_bytes = (size_t)B_ * S_ * sizeof(float);
    const bool precomp = (ws_size >= rnorm_bytes);

    if (precomp) {
        knorm_kernel<<<(B_ * S_) / 16, 256, 0, stream>>>(key, rnorm);
        delta_kernel<true><<<256, 256, 0, stream>>>(memory, key, value, rnorm, out);
    } else {
        delta_kernel<false><<<256, 256, 0, stream>>>(memory, key, value, nullptr, out);
    }
}